// Round 20
// baseline (158.063 us; speedup 1.0000x reference)
//
#include <hip/hip_runtime.h>
#include <math.h>

// Problem constants
static constexpr int Bsz = 4;
static constexpr int Tn  = 2048;
static constexpr int Cn  = 1024;
static constexpr int Hn  = 16;
static constexpr int Dn  = 64;   // head dim

typedef __attribute__((ext_vector_type(8))) short bf16x8;
typedef __attribute__((ext_vector_type(4))) float f32x4;

#define MFMA16(a, b, c) __builtin_amdgcn_mfma_f32_16x16x32_bf16((a), (b), (c), 0, 0, 0)

static constexpr float kQScale = 0.18033688f;  // 0.125 * log2(e)

__device__ __forceinline__ unsigned short f2bf(float f) {
  unsigned u = __float_as_uint(f);
  unsigned r = (u + 0x7fffu + ((u >> 16) & 1u)) >> 16;  // RNE
  return (unsigned short)r;
}

__device__ __forceinline__ unsigned cvtpk_bf16(float lo, float hi) {
  unsigned r;
  asm("v_cvt_pk_bf16_f32 %0, %1, %2" : "=v"(r) : "v"(lo), "v"(hi));
  return r;
}

__device__ __forceinline__ void load_lds16(const void* g, void* l) {
  __builtin_amdgcn_global_load_lds(
      (const __attribute__((address_space(1))) void*)g,
      (__attribute__((address_space(3))) void*)l, 16, 0, 0);
}

// ---------------------------------------------------------------------------
// Merged prep: z<4 -> W[z] [K][N] fp32 -> Wt [N][K] bf16 (LDS transpose);
// z>=4  -> x fp32 -> bf16, 8 elems/thread. Grid (16, 16, 20).
// ---------------------------------------------------------------------------
__global__ __launch_bounds__(256) void prep_k(
    const float* __restrict__ x, unsigned short* __restrict__ xb,
    const float* __restrict__ w0, const float* __restrict__ w1,
    const float* __restrict__ w2, const float* __restrict__ w3,
    unsigned short* __restrict__ o0, unsigned short* __restrict__ o1,
    unsigned short* __restrict__ o2, unsigned short* __restrict__ o3) {
  __shared__ unsigned short Ts[64][65];
  const int z = blockIdx.z;
  if (z >= 4) {
    const int bi = (z - 4) * 256 + blockIdx.y * 16 + blockIdx.x;
    const int i = bi * 256 + threadIdx.x;  // 8 elems each
    const float4 a = ((const float4*)x)[i * 2 + 0];
    const float4 b = ((const float4*)x)[i * 2 + 1];
    uint4 o;
    o.x = cvtpk_bf16(a.x, a.y);
    o.y = cvtpk_bf16(a.z, a.w);
    o.z = cvtpk_bf16(b.x, b.y);
    o.w = cvtpk_bf16(b.z, b.w);
    ((uint4*)xb)[i] = o;
    return;
  }
  const float* W;
  unsigned short* O;
  switch (z) {
    case 0: W = w0; O = o0; break;
    case 1: W = w1; O = o1; break;
    case 2: W = w2; O = o2; break;
    default: W = w3; O = o3; break;
  }
  const int k0 = blockIdx.y * 64, n0 = blockIdx.x * 64;
  const int tid = threadIdx.x;
  const int cr = tid >> 4, cc = (tid & 15) * 4;
#pragma unroll
  for (int p = 0; p < 4; ++p) {
    const int r = p * 16 + cr;
    const float4 v = *(const float4*)&W[(size_t)(k0 + r) * Cn + n0 + cc];
    Ts[r][cc + 0] = f2bf(v.x);
    Ts[r][cc + 1] = f2bf(v.y);
    Ts[r][cc + 2] = f2bf(v.z);
    Ts[r][cc + 3] = f2bf(v.w);
  }
  __syncthreads();
#pragma unroll
  for (int p = 0; p < 4; ++p) {
    const int n = p * 16 + cr;
    ushort4 o;
    o.x = Ts[cc + 0][n];
    o.y = Ts[cc + 1][n];
    o.z = Ts[cc + 2][n];
    o.w = Ts[cc + 3][n];
    *(ushort4*)&O[(size_t)(n0 + n) * Cn + k0 + cc] = o;
  }
}

// ---------------------------------------------------------------------------
// 128^2-tile GEMM core (BK=64): double-buffered split-wait + T2 swizzle.
// Used by proj. (R12 lesson: 256^2 variant regressed at this shape.)
// ---------------------------------------------------------------------------
__device__ __forceinline__ void gemm_core(
    const unsigned short* __restrict__ A, const unsigned short* __restrict__ Bt,
    int row0, int col0, unsigned short* As, unsigned short* Bs,
    f32x4 acc[4][4]) {
  const int tid = threadIdx.x;
  const int lane = tid & 63, w = tid >> 6;
  const int wm = w >> 1, wn = w & 1;
  const int lr = lane & 15, lg = lane >> 4;

  auto stage = [&](int buf, int k0) {
#pragma unroll
    for (int it = 0; it < 4; ++it) {
      const int c = it * 256 + tid;
      const int r = c >> 3;
      const int lc = (c & 7) ^ (r & 7);   // pre-swizzled source chunk
      load_lds16(A + (size_t)(row0 + r) * Cn + k0 + lc * 8,
                 &As[buf * 8192 + c * 8]);
    }
#pragma unroll
    for (int it = 0; it < 4; ++it) {
      const int c = it * 256 + tid;
      const int r = c >> 3;
      const int lc = (c & 7) ^ (r & 7);
      load_lds16(Bt + (size_t)(col0 + r) * Cn + k0 + lc * 8,
                 &Bs[buf * 8192 + c * 8]);
    }
  };

  stage(0, 0);
  for (int ki = 0; ki < 16; ++ki) {
    const int cur = ki & 1;
    const bool pf = (ki < 15);
    if (pf) stage(cur ^ 1, (ki + 1) * 64);
    if (pf) asm volatile("s_waitcnt vmcnt(8)" ::: "memory");
    else    asm volatile("s_waitcnt vmcnt(0)" ::: "memory");
    __builtin_amdgcn_s_barrier();
#pragma unroll
    for (int ks = 0; ks < 2; ++ks) {
      bf16x8 af[4], bfr[4];
#pragma unroll
      for (int mi = 0; mi < 4; ++mi)
        af[mi] = *(const bf16x8*)
            &As[cur * 8192 + (wm * 64 + mi * 16 + lr) * 64 +
                (((ks * 4 + lg) ^ (lr & 7)) << 3)];
#pragma unroll
      for (int ni = 0; ni < 4; ++ni)
        bfr[ni] = *(const bf16x8*)
            &Bs[cur * 8192 + (wn * 64 + ni * 16 + lr) * 64 +
                (((ks * 4 + lg) ^ (lr & 7)) << 3)];
#pragma unroll
      for (int mi = 0; mi < 4; ++mi)
#pragma unroll
        for (int ni = 0; ni < 4; ++ni)
          acc[mi][ni] = MFMA16(af[mi], bfr[ni], acc[mi][ni]);
    }
    if (pf) __builtin_amdgcn_s_barrier();
  }
}

// ---------------------------------------------------------------------------
// FUSED QKV, 3-PHASE split-wait (T3/T4, m248 pattern): one 128x128 tile of
// Q/K/V per block; A staged once, af reused for 3 B operands.
// Issue order per iter: [A,B0(ki+1) | B1(ki+1) | B2(ki+1)]; waits:
//   P0: vmcnt(4)  -> drains A,B0(ki)  (issued 1 full iteration earlier)
//   P1: vmcnt(6)  -> drains B1(ki)    (tail: vmcnt(2))
//   P2: vmcnt(6)  -> drains B2(ki)    (tail: vmcnt(0))
// 8 loads always in flight; every awaited load >=1 iter old. All buffers
// double-buffered (no WAR: overwrites land >=2 barriers after last reads).
// Q/K epilogues via LDS transpose (coalesced). Grid (64, 8): XCD = x%8.
// ---------------------------------------------------------------------------
__global__ __launch_bounds__(256, 2) void qkv_fused_k(
    const unsigned short* __restrict__ A,
    const unsigned short* __restrict__ Wq, const unsigned short* __restrict__ Wk,
    const unsigned short* __restrict__ Wv,
    const float* __restrict__ bq, const float* __restrict__ bk,
    const float* __restrict__ bv,
    unsigned short* __restrict__ Qo, unsigned short* __restrict__ Ko,
    unsigned short* __restrict__ Vo) {
  __shared__ unsigned short As[2][128 * 32];      // 16 KB
  __shared__ unsigned short Bs[2][3][128 * 32];   // 48 KB
  const int tid = threadIdx.x, lane = tid & 63, w = tid >> 6;
  const int wm = w >> 1, wn = w & 1;
  const int lr = lane & 15, lg = lane >> 4;
  const int row0 = blockIdx.x * 128, col0 = blockIdx.y * 128;

  auto stage_A = [&](int buf, int k0) {
#pragma unroll
    for (int it = 0; it < 2; ++it) {
      const int c = it * 256 + tid;
      const int r = c >> 2;
      const int lc = (c & 3) ^ ((r >> 1) & 3);
      load_lds16(A + (size_t)(row0 + r) * Cn + k0 + lc * 8, &As[buf][c * 8]);
    }
  };
  auto stage_B0 = [&](int buf, int k0) {
#pragma unroll
    for (int it = 0; it < 2; ++it) {
      const int c = it * 256 + tid;
      const int r = c >> 2;
      const int lc = (c & 3) ^ ((r >> 1) & 3);
      load_lds16(Wq + (size_t)(col0 + r) * Cn + k0 + lc * 8, &Bs[buf][0][c * 8]);
    }
  };
  auto stage_B1 = [&](int buf, int k0) {
#pragma unroll
    for (int it = 0; it < 2; ++it) {
      const int c = it * 256 + tid;
      const int r = c >> 2;
      const int lc = (c & 3) ^ ((r >> 1) & 3);
      load_lds16(Wk + (size_t)(col0 + r) * Cn + k0 + lc * 8, &Bs[buf][1][c * 8]);
    }
  };
  auto stage_B2 = [&](int buf, int k0) {
#pragma unroll
    for (int it = 0; it < 2; ++it) {
      const int c = it * 256 + tid;
      const int r = c >> 2;
      const int lc = (c & 3) ^ ((r >> 1) & 3);
      load_lds16(Wv + (size_t)(col0 + r) * Cn + k0 + lc * 8, &Bs[buf][2][c * 8]);
    }
  };

  const f32x4 fz = {0.f, 0.f, 0.f, 0.f};
  f32x4 acc0[4][4], acc1[4][4], acc2[4][4];
#pragma unroll
  for (int i = 0; i < 4; ++i)
#pragma unroll
    for (int j = 0; j < 4; ++j) { acc0[i][j] = fz; acc1[i][j] = fz; acc2[i][j] = fz; }

  // prologue: tile 0, issue order A,B0 | B1 | B2 (matches steady state)
  stage_A(0, 0); stage_B0(0, 0);
  stage_B1(0, 0);
  stage_B2(0, 0);

  for (int ki = 0; ki < 32; ++ki) {
    const int cur = ki & 1;
    const bool pf = (ki < 31);
    const int nk0 = (ki + 1) * 32;
    const int kchunk = (lg ^ ((lr >> 1) & 3)) << 3;

    // ---- P0: A + B0 (Q) ----
    asm volatile("s_waitcnt vmcnt(4)" ::: "memory");  // A,B0(ki) landed
    __builtin_amdgcn_s_barrier();
    if (pf) { stage_A(cur ^ 1, nk0); stage_B0(cur ^ 1, nk0); }
    bf16x8 af[4];
#pragma unroll
    for (int mi = 0; mi < 4; ++mi)
      af[mi] = *(const bf16x8*)
          &As[cur][(wm * 64 + mi * 16 + lr) * 32 + kchunk];
    {
      bf16x8 bfr[4];
#pragma unroll
      for (int ni = 0; ni < 4; ++ni)
        bfr[ni] = *(const bf16x8*)
            &Bs[cur][0][(wn * 64 + ni * 16 + lr) * 32 + kchunk];
      __builtin_amdgcn_s_setprio(1);
#pragma unroll
      for (int mi = 0; mi < 4; ++mi)
#pragma unroll
        for (int ni = 0; ni < 4; ++ni)
          acc0[mi][ni] = MFMA16(af[mi], bfr[ni], acc0[mi][ni]);
      __builtin_amdgcn_s_setprio(0);
    }

    // ---- P1: B1 (K) ----
    if (pf) asm volatile("s_waitcnt vmcnt(6)" ::: "memory");  // B1(ki) landed
    else    asm volatile("s_waitcnt vmcnt(2)" ::: "memory");
    __builtin_amdgcn_s_barrier();
    if (pf) stage_B1(cur ^ 1, nk0);
    {
      bf16x8 bfr[4];
#pragma unroll
      for (int ni = 0; ni < 4; ++ni)
        bfr[ni] = *(const bf16x8*)
            &Bs[cur][1][(wn * 64 + ni * 16 + lr) * 32 + kchunk];
      __builtin_amdgcn_s_setprio(1);
#pragma unroll
      for (int mi = 0; mi < 4; ++mi)
#pragma unroll
        for (int ni = 0; ni < 4; ++ni)
          acc1[mi][ni] = MFMA16(af[mi], bfr[ni], acc1[mi][ni]);
      __builtin_amdgcn_s_setprio(0);
    }

    // ---- P2: B2 (V) ----
    if (pf) asm volatile("s_waitcnt vmcnt(6)" ::: "memory");  // B2(ki) landed
    else    asm volatile("s_waitcnt vmcnt(0)" ::: "memory");
    __builtin_amdgcn_s_barrier();
    if (pf) stage_B2(cur ^ 1, nk0);
    {
      bf16x8 bfr[4];
#pragma unroll
      for (int ni = 0; ni < 4; ++ni)
        bfr[ni] = *(const bf16x8*)
            &Bs[cur][2][(wn * 64 + ni * 16 + lr) * 32 + kchunk];
      __builtin_amdgcn_s_setprio(1);
#pragma unroll
      for (int mi = 0; mi < 4; ++mi)
#pragma unroll
        for (int ni = 0; ni < 4; ++ni)
          acc2[mi][ni] = MFMA16(af[mi], bfr[ni], acc2[mi][ni]);
      __builtin_amdgcn_s_setprio(0);
    }
  }

  // ---- epilogue ----
  const int b = row0 >> 11;
  const int t0w = (row0 & (Tn - 1)) + wm * 64;   // wave's first t
  const int h = (col0 >> 6) + wn;                // wave's head

  // V^T (acc2): 4 consecutive t at fixed d -> one 8B store
#pragma unroll
  for (int mi = 0; mi < 4; ++mi) {
#pragma unroll
    for (int ni = 0; ni < 4; ++ni) {
      const int d = ni * 16 + lr;
      const float bv_ = bv[col0 + wn * 64 + d];
      const int t0 = t0w + mi * 16 + lg * 4;
      ushort4 o4;
      o4.x = f2bf(acc2[mi][ni][0] + bv_);
      o4.y = f2bf(acc2[mi][ni][1] + bv_);
      o4.z = f2bf(acc2[mi][ni][2] + bv_);
      o4.w = f2bf(acc2[mi][ni][3] + bv_);
      *(ushort4*)&Vo[(((size_t)b * Hn + h) * Dn + d) * Tn + t0] = o4;
    }
  }

  // Q/K via LDS transpose: wave-private [64][68] bf16 scratch in Bs
  __syncthreads();
  unsigned short* epi = &Bs[0][0][0] + w * 4352;

  // Q (pre-scaled)
  {
#pragma unroll
    for (int mi = 0; mi < 4; ++mi)
#pragma unroll
      for (int ni = 0; ni < 4; ++ni) {
        const float bv_ = bq[col0 + wn * 64 + ni * 16 + lr];
#pragma unroll
        for (int r = 0; r < 4; ++r)
          epi[(mi * 16 + lg * 4 + r) * 68 + ni * 16 + lr] =
              f2bf((acc0[mi][ni][r] + bv_) * kQScale);
      }
    asm volatile("s_waitcnt lgkmcnt(0)" ::: "memory");
#pragma unroll
    for (int j = 0; j < 8; ++j) {
      const int t = (lane >> 3) + 8 * j;
      const int ck = lane & 7;
      const bf16x8 v = *(const bf16x8*)&epi[t * 68 + ck * 8];
      *(bf16x8*)&Qo[((((size_t)b * Hn + h) * Tn + t0w + t) << 6) + ck * 8] = v;
    }
  }
  // K
  {
#pragma unroll
    for (int mi = 0; mi < 4; ++mi)
#pragma unroll
      for (int ni = 0; ni < 4; ++ni) {
        const float bv_ = bk[col0 + wn * 64 + ni * 16 + lr];
#pragma unroll
        for (int r = 0; r < 4; ++r)
          epi[(mi * 16 + lg * 4 + r) * 68 + ni * 16 + lr] =
              f2bf(acc1[mi][ni][r] + bv_);
      }
    asm volatile("s_waitcnt lgkmcnt(0)" ::: "memory");
#pragma unroll
    for (int j = 0; j < 8; ++j) {
      const int t = (lane >> 3) + 8 * j;
      const int ck = lane & 7;
      const bf16x8 v = *(const bf16x8*)&epi[t * 68 + ck * 8];
      *(bf16x8*)&Ko[((((size_t)b * Hn + h) * Tn + t0w + t) << 6) + ck * 8] = v;
    }
  }
}

// ---------------------------------------------------------------------------
// Output projection: fp32 out = Yb @ Wpt^T + bp.  Grid (64, 8).
// ---------------------------------------------------------------------------
__global__ __launch_bounds__(256, 2) void proj_gemm_k(
    const unsigned short* __restrict__ A, const unsigned short* __restrict__ Bt,
    const float* __restrict__ bias, float* __restrict__ out) {
  __shared__ unsigned short As[2 * 128 * 64];
  __shared__ unsigned short Bs[2 * 128 * 64];
  const int row0 = blockIdx.x * 128, col0 = blockIdx.y * 128;
  const f32x4 fz = {0.f, 0.f, 0.f, 0.f};
  f32x4 acc[4][4];
#pragma unroll
  for (int i = 0; i < 4; ++i)
#pragma unroll
    for (int j = 0; j < 4; ++j) acc[i][j] = fz;

  gemm_core(A, Bt, row0, col0, As, Bs, acc);

  const int lane = threadIdx.x & 63, w = threadIdx.x >> 6;
  const int wm = w >> 1, wn = w & 1;
  const int lr = lane & 15, lg = lane >> 4;
#pragma unroll
  for (int mi = 0; mi < 4; ++mi) {
#pragma unroll
    for (int ni = 0; ni < 4; ++ni) {
      const int col = col0 + wn * 64 + ni * 16 + lr;
      const float bv_ = bias[col];
#pragma unroll
      for (int r = 0; r < 4; ++r) {
        const int row = row0 + wm * 64 + mi * 16 + lg * 4 + r;
        out[(size_t)row * Cn + col] = acc[mi][ni][r] + bv_;
      }
    }
  }
}

// ---------------------------------------------------------------------------
// Flash attention (R19, unchanged): bf16 MFMA, swapped-QK^T, exp2-direct
// softmax, single-buffer V (32 KB LDS), l via MFMA (P . ones).
// Grid (64, 32): XCD = bh%8; qt reversed (LPT). Y epilogue via LDS-transpose.
// ---------------------------------------------------------------------------
__global__ __launch_bounds__(256, 4) void attn_mfma_k(
    const unsigned short* __restrict__ Q, const unsigned short* __restrict__ K,
    const unsigned short* __restrict__ Vt, unsigned short* __restrict__ Y) {
  __shared__ unsigned short Ks[2][64 * 64];   // 16 KB
  __shared__ unsigned short Vs[64 * 64];      //  8 KB (V^T tile: [d][key])
  __shared__ unsigned short Ps[4][16 * 64];   //  8 KB per-wave P: [q][key]
  const int tid = threadIdx.x, lane = tid & 63, w = tid >> 6;
  const int lr = lane & 15, lg = lane >> 4;
  const int bh = blockIdx.x;                       // XCD-local heads
  const int qt = (int)gridDim.y - 1 - blockIdx.y;  // heavy blocks first
  const size_t base = (size_t)bh * Tn * Dn;

  bf16x8 qf[2];
  const int qrow = qt * 64 + w * 16 + lr;   // this lane's q (global)
#pragma unroll
  for (int ks = 0; ks < 2; ++ks)
    qf[ks] = *(const bf16x8*)&Q[base + (size_t)qrow * Dn + ks * 32 + lg * 8];

  // constant all-ones bf16 fragment (B operand for the l-MFMA)
  const short one_bf = (short)0x3F80;
  const bf16x8 onesf = {one_bf, one_bf, one_bf, one_bf,
                        one_bf, one_bf, one_bf, one_bf};

  auto stage_K = [&](int buf, int kt) {
#pragma unroll
    for (int it = 0; it < 2; ++it) {
      const int c = it * 256 + tid;
      const int r = c >> 3;
      const int lc = (c & 7) ^ (r & 7);
      load_lds16(K + base + (size_t)(kt * 64 + r) * Dn + lc * 8, &Ks[buf][c * 8]);
    }
  };
  auto stage_V = [&](int kt) {
#pragma unroll
    for (int it = 0; it < 2; ++it) {
      const int c = it * 256 + tid;
      const int r = c >> 3;
      const int lc = (c & 7) ^ (r & 7);
      load_lds16(Vt + base + (size_t)r * Tn + kt * 64 + lc * 8, &Vs[c * 8]);
    }
  };

  const f32x4 fz = {0.f, 0.f, 0.f, 0.f};
  f32x4 oacc[4];
#pragma unroll
  for (int i = 0; i < 4; ++i) oacc[i] = fz;
  f32x4 acc_l = fz;   // l[q=lg*4+i] accumulated on the MFMA pipe

  // prologue: K(0) only (V(0) staged inside iteration 0)
  stage_K(0, 0);
  asm volatile("s_waitcnt vmcnt(0)" ::: "memory");
  __builtin_amdgcn_s_barrier();

  for (int kt = 0; kt <= qt; ++kt) {
    const int cur = kt & 1;
    const bool pf = (kt < qt);
    stage_V(kt);                       // V for THIS tile (drained mid-iter)
    if (pf) stage_K(cur ^ 1, kt + 1);  // K prefetch (drained end-of-iter)

    // ---- S^T = K . Q^T ----
    f32x4 s[4];
#pragma unroll
    for (int ni = 0; ni < 4; ++ni) s[ni] = fz;
    __builtin_amdgcn_s_setprio(1);
#pragma unroll
    for (int ni = 0; ni < 4; ++ni)
#pragma unroll
      for (int ks = 0; ks < 2; ++ks) {
        const bf16x8 kf = *(const bf16x8*)
            &Ks[cur][(ni * 16 + lr) * 64 + (((ks * 4 + lg) ^ (lr & 7)) << 3)];
        s[ni] = MFMA16(kf, qf[ks], s[ni]);
      }
    __builtin_amdgcn_s_setprio(0);

    const bool diag = (kt == qt);
    uint2 pw[4];
#pragma unroll
    for (int ni = 0; ni < 4; ++ni) {
      float p[4];
#pragma unroll
      for (int r = 0; r < 4; ++r) {
        float v = s[ni][r];
        if (diag) {
          const int gk = kt * 64 + ni * 16 + lg * 4 + r;
          if (gk > qrow) v = -1e30f;  // exp2 -> 0
        }
        p[r] = exp2f(v);
      }
      pw[ni].x = cvtpk_bf16(p[0], p[1]);
      pw[ni].y = cvtpk_bf16(p[2], p[3]);
    }

#pragma unroll
    for (int ni = 0; ni < 4; ++ni) {
      const int byte = lr * 128 + ((((ni * 2) + (lg >> 1)) ^ (lr & 7)) << 4) +
                       ((lg & 1) << 3);
      *(uint2*)((char*)&Ps[w][0] + byte) = pw[ni];
    }

    // ---- mid wait: V(kt) done (issued first this iter -> oldest) ----
    if (pf) asm volatile("s_waitcnt vmcnt(2)" ::: "memory");
    else    asm volatile("s_waitcnt vmcnt(0)" ::: "memory");
    __builtin_amdgcn_s_barrier();

    // ---- PV (+ l = P . ones on the MFMA pipe) ----
    __builtin_amdgcn_s_setprio(1);
#pragma unroll
    for (int ks = 0; ks < 2; ++ks) {
      const bf16x8 pa = *(const bf16x8*)
          &Ps[w][lr * 64 + (((ks * 4 + lg) ^ (lr & 7)) << 3)];
      acc_l = MFMA16(pa, onesf, acc_l);
#pragma unroll
      for (int nd = 0; nd < 4; ++nd) {
        const bf16x8 vf = *(const bf16x8*)
            &Vs[(nd * 16 + lr) * 64 + (((ks * 4 + lg) ^ (lr & 7)) << 3)];
        oacc[nd] = MFMA16(pa, vf, oacc[nd]);
      }
    }
    __builtin_amdgcn_s_setprio(0);

    // ---- end: K(kt+1) done (issued ~500cy ago); protect Vs/Ks WAR ----
    if (pf) {
      asm volatile("s_waitcnt vmcnt(0)" ::: "memory");
      __builtin_amdgcn_s_barrier();
    }
  }

  // epilogue: acc_l[i] = l for q = lg*4+i (no cross-lane reduce needed).
  const int b = bh >> 4, h = bh & 15;
  unsigned short* epi = &Ks[0][0] + w * 1152;
#pragma unroll
  for (int i = 0; i < 4; ++i) {
    const float inv = 1.f / acc_l[i];
#pragma unroll
    for (int nd = 0; nd < 4; ++nd)
      epi[(lg * 4 + i) * 68 + nd * 16 + lr] = f2bf(oacc[nd][i] * inv);
  }
  asm volatile("s_waitcnt lgkmcnt(0)" ::: "memory");
#pragma unroll
  for (int j = 0; j < 2; ++j) {
    const int tl = lane >> 2;
    const int ck = (lane & 3) + 4 * j;
    const bf16x8 v = *(const bf16x8*)&epi[tl * 68 + ck * 8];
    const int t = qt * 64 + w * 16 + tl;
    *(bf16x8*)&Y[((size_t)b * Tn + t) * Cn + h * Dn + ck * 8] = v;
  }
}

// ---------------------------------------------------------------------------
extern "C" void kernel_launch(void* const* d_in, const int* in_sizes, int n_in,
                              void* d_out, int out_size, void* d_ws, size_t ws_size,
                              hipStream_t stream) {
  const float* x  = (const float*)d_in[0];
  const float* Wq = (const float*)d_in[1];
  const float* bq = (const float*)d_in[2];
  const float* Wk = (const float*)d_in[3];
  const float* bk = (const float*)d_in[4];
  const float* Wv = (const float*)d_in[5];
  const float* bv = (const float*)d_in[6];
  const float* Wp = (const float*)d_in[7];
  const float* bp = (const float*)d_in[8];
  float* out = (float*)d_out;

  const size_t xe = (size_t)Bsz * Tn * Cn;  // 8,388,608
  const size_t we = (size_t)Cn * Cn;        // 1,048,576
  unsigned short* p = (unsigned short*)d_ws;
  unsigned short* xb  = p; p += xe;
  unsigned short* Wqt = p; p += we;
  unsigned short* Wkt = p; p += we;
  unsigned short* Wvt = p; p += we;
  unsigned short* Wpt = p; p += we;
  unsigned short* Qb  = p; p += xe;
  unsigned short* Kb  = p; p += xe;
  unsigned short* Vtb = p; p += xe;
  unsigned short* Yb  = p; p += xe;

  prep_k<<<dim3(16, 16, 20), dim3(256), 0, stream>>>(
      x, xb, Wq, Wk, Wv, Wp, Wqt, Wkt, Wvt, Wpt);

  qkv_fused_k<<<dim3((Bsz * Tn) / 128, Cn / 128), dim3(256), 0, stream>>>(
      xb, Wqt, Wkt, Wvt, bq, bk, bv, Qb, Kb, Vtb);

  attn_mfma_k<<<dim3(Bsz * Hn, Tn / 64), dim3(256), 0, stream>>>(Qb, Kb, Vtb, Yb);

  proj_gemm_k<<<dim3((Bsz * Tn) / 128, Cn / 128), dim3(256), 0, stream>>>(
      Yb, Wpt, bp, out);
}

// Round 21
// 151.138 us; speedup vs baseline: 1.0458x; 1.0458x over previous
//
#include <hip/hip_runtime.h>
#include <math.h>

// Problem constants
static constexpr int Bsz = 4;
static constexpr int Tn  = 2048;
static constexpr int Cn  = 1024;
static constexpr int Hn  = 16;
static constexpr int Dn  = 64;   // head dim

typedef __attribute__((ext_vector_type(8))) short bf16x8;
typedef __attribute__((ext_vector_type(4))) float f32x4;

#define MFMA16(a, b, c) __builtin_amdgcn_mfma_f32_16x16x32_bf16((a), (b), (c), 0, 0, 0)

static constexpr float kQScale = 0.18033688f;  // 0.125 * log2(e)

__device__ __forceinline__ unsigned short f2bf(float f) {
  unsigned u = __float_as_uint(f);
  unsigned r = (u + 0x7fffu + ((u >> 16) & 1u)) >> 16;  // RNE
  return (unsigned short)r;
}

__device__ __forceinline__ unsigned cvtpk_bf16(float lo, float hi) {
  unsigned r;
  asm("v_cvt_pk_bf16_f32 %0, %1, %2" : "=v"(r) : "v"(lo), "v"(hi));
  return r;
}

__device__ __forceinline__ void load_lds16(const void* g, void* l) {
  __builtin_amdgcn_global_load_lds(
      (const __attribute__((address_space(1))) void*)g,
      (__attribute__((address_space(3))) void*)l, 16, 0, 0);
}

// ---------------------------------------------------------------------------
// Merged prep: z<4 -> W[z] [K][N] fp32 -> Wt [N][K] bf16 (LDS transpose);
// z>=4  -> x fp32 -> bf16, 8 elems/thread. Grid (16, 16, 20).
// ---------------------------------------------------------------------------
__global__ __launch_bounds__(256) void prep_k(
    const float* __restrict__ x, unsigned short* __restrict__ xb,
    const float* __restrict__ w0, const float* __restrict__ w1,
    const float* __restrict__ w2, const float* __restrict__ w3,
    unsigned short* __restrict__ o0, unsigned short* __restrict__ o1,
    unsigned short* __restrict__ o2, unsigned short* __restrict__ o3) {
  __shared__ unsigned short Ts[64][65];
  const int z = blockIdx.z;
  if (z >= 4) {
    const int bi = (z - 4) * 256 + blockIdx.y * 16 + blockIdx.x;
    const int i = bi * 256 + threadIdx.x;  // 8 elems each
    const float4 a = ((const float4*)x)[i * 2 + 0];
    const float4 b = ((const float4*)x)[i * 2 + 1];
    uint4 o;
    o.x = cvtpk_bf16(a.x, a.y);
    o.y = cvtpk_bf16(a.z, a.w);
    o.z = cvtpk_bf16(b.x, b.y);
    o.w = cvtpk_bf16(b.z, b.w);
    ((uint4*)xb)[i] = o;
    return;
  }
  const float* W;
  unsigned short* O;
  switch (z) {
    case 0: W = w0; O = o0; break;
    case 1: W = w1; O = o1; break;
    case 2: W = w2; O = o2; break;
    default: W = w3; O = o3; break;
  }
  const int k0 = blockIdx.y * 64, n0 = blockIdx.x * 64;
  const int tid = threadIdx.x;
  const int cr = tid >> 4, cc = (tid & 15) * 4;
#pragma unroll
  for (int p = 0; p < 4; ++p) {
    const int r = p * 16 + cr;
    const float4 v = *(const float4*)&W[(size_t)(k0 + r) * Cn + n0 + cc];
    Ts[r][cc + 0] = f2bf(v.x);
    Ts[r][cc + 1] = f2bf(v.y);
    Ts[r][cc + 2] = f2bf(v.z);
    Ts[r][cc + 3] = f2bf(v.w);
  }
  __syncthreads();
#pragma unroll
  for (int p = 0; p < 4; ++p) {
    const int n = p * 16 + cr;
    ushort4 o;
    o.x = Ts[cc + 0][n];
    o.y = Ts[cc + 1][n];
    o.z = Ts[cc + 2][n];
    o.w = Ts[cc + 3][n];
    *(ushort4*)&O[(size_t)(n0 + n) * Cn + k0 + cc] = o;
  }
}

// ---------------------------------------------------------------------------
// 128^2-tile GEMM core (BK=64): double-buffered split-wait + T2 swizzle.
// Used by proj. (R12 lesson: 256^2 variant regressed at this shape.)
// ---------------------------------------------------------------------------
__device__ __forceinline__ void gemm_core(
    const unsigned short* __restrict__ A, const unsigned short* __restrict__ Bt,
    int row0, int col0, unsigned short* As, unsigned short* Bs,
    f32x4 acc[4][4]) {
  const int tid = threadIdx.x;
  const int lane = tid & 63, w = tid >> 6;
  const int wm = w >> 1, wn = w & 1;
  const int lr = lane & 15, lg = lane >> 4;

  auto stage = [&](int buf, int k0) {
#pragma unroll
    for (int it = 0; it < 4; ++it) {
      const int c = it * 256 + tid;
      const int r = c >> 3;
      const int lc = (c & 7) ^ (r & 7);   // pre-swizzled source chunk
      load_lds16(A + (size_t)(row0 + r) * Cn + k0 + lc * 8,
                 &As[buf * 8192 + c * 8]);
    }
#pragma unroll
    for (int it = 0; it < 4; ++it) {
      const int c = it * 256 + tid;
      const int r = c >> 3;
      const int lc = (c & 7) ^ (r & 7);
      load_lds16(Bt + (size_t)(col0 + r) * Cn + k0 + lc * 8,
                 &Bs[buf * 8192 + c * 8]);
    }
  };

  stage(0, 0);
  for (int ki = 0; ki < 16; ++ki) {
    const int cur = ki & 1;
    const bool pf = (ki < 15);
    if (pf) stage(cur ^ 1, (ki + 1) * 64);
    if (pf) asm volatile("s_waitcnt vmcnt(8)" ::: "memory");
    else    asm volatile("s_waitcnt vmcnt(0)" ::: "memory");
    __builtin_amdgcn_s_barrier();
#pragma unroll
    for (int ks = 0; ks < 2; ++ks) {
      bf16x8 af[4], bfr[4];
#pragma unroll
      for (int mi = 0; mi < 4; ++mi)
        af[mi] = *(const bf16x8*)
            &As[cur * 8192 + (wm * 64 + mi * 16 + lr) * 64 +
                (((ks * 4 + lg) ^ (lr & 7)) << 3)];
#pragma unroll
      for (int ni = 0; ni < 4; ++ni)
        bfr[ni] = *(const bf16x8*)
            &Bs[cur * 8192 + (wn * 64 + ni * 16 + lr) * 64 +
                (((ks * 4 + lg) ^ (lr & 7)) << 3)];
#pragma unroll
      for (int mi = 0; mi < 4; ++mi)
#pragma unroll
        for (int ni = 0; ni < 4; ++ni)
          acc[mi][ni] = MFMA16(af[mi], bfr[ni], acc[mi][ni]);
    }
    if (pf) __builtin_amdgcn_s_barrier();
  }
}

// ---------------------------------------------------------------------------
// FUSED QKV (R19 structure, reverted from R20 3-phase): one 128x128 tile of
// Q/K/V per block; A staged once, af reused for 3 B operands; bulk stage +
// vmcnt(8) split-wait, 2 barriers/iter. setprio REMOVED (m190: null-to-
// negative on lockstep barrier-synced GEMM; only pays with phase-split).
// Q/K epilogues via LDS transpose (coalesced). Grid (64, 8): XCD = x%8.
// ---------------------------------------------------------------------------
__global__ __launch_bounds__(256, 2) void qkv_fused_k(
    const unsigned short* __restrict__ A,
    const unsigned short* __restrict__ Wq, const unsigned short* __restrict__ Wk,
    const unsigned short* __restrict__ Wv,
    const float* __restrict__ bq, const float* __restrict__ bk,
    const float* __restrict__ bv,
    unsigned short* __restrict__ Qo, unsigned short* __restrict__ Ko,
    unsigned short* __restrict__ Vo) {
  __shared__ unsigned short As[2][128 * 32];      // 16 KB
  __shared__ unsigned short Bs[2][3][128 * 32];   // 48 KB
  const int tid = threadIdx.x, lane = tid & 63, w = tid >> 6;
  const int wm = w >> 1, wn = w & 1;
  const int lr = lane & 15, lg = lane >> 4;
  const int row0 = blockIdx.x * 128, col0 = blockIdx.y * 128;

  auto stage = [&](int buf, int k0) {
    const unsigned short* Ws[3] = {Wq, Wk, Wv};
#pragma unroll
    for (int it = 0; it < 2; ++it) {
      const int c = it * 256 + tid;
      const int r = c >> 2;
      const int lc = (c & 3) ^ ((r >> 1) & 3);
      load_lds16(A + (size_t)(row0 + r) * Cn + k0 + lc * 8, &As[buf][c * 8]);
    }
#pragma unroll
    for (int z = 0; z < 3; ++z)
#pragma unroll
      for (int it = 0; it < 2; ++it) {
        const int c = it * 256 + tid;
        const int r = c >> 2;
        const int lc = (c & 3) ^ ((r >> 1) & 3);
        load_lds16(Ws[z] + (size_t)(col0 + r) * Cn + k0 + lc * 8,
                   &Bs[buf][z][c * 8]);
      }
  };

  const f32x4 fz = {0.f, 0.f, 0.f, 0.f};
  f32x4 acc0[4][4], acc1[4][4], acc2[4][4];
#pragma unroll
  for (int i = 0; i < 4; ++i)
#pragma unroll
    for (int j = 0; j < 4; ++j) { acc0[i][j] = fz; acc1[i][j] = fz; acc2[i][j] = fz; }

  stage(0, 0);
  for (int ki = 0; ki < 32; ++ki) {
    const int cur = ki & 1;
    const bool pf = (ki < 31);
    if (pf) stage(cur ^ 1, (ki + 1) * 32);
    if (pf) asm volatile("s_waitcnt vmcnt(8)" ::: "memory");
    else    asm volatile("s_waitcnt vmcnt(0)" ::: "memory");
    __builtin_amdgcn_s_barrier();

    const int kchunk = (lg ^ ((lr >> 1) & 3)) << 3;
    bf16x8 af[4];
#pragma unroll
    for (int mi = 0; mi < 4; ++mi)
      af[mi] = *(const bf16x8*)
          &As[cur][(wm * 64 + mi * 16 + lr) * 32 + kchunk];

    {
      bf16x8 bfr[4];
#pragma unroll
      for (int ni = 0; ni < 4; ++ni)
        bfr[ni] = *(const bf16x8*)
            &Bs[cur][0][(wn * 64 + ni * 16 + lr) * 32 + kchunk];
#pragma unroll
      for (int mi = 0; mi < 4; ++mi)
#pragma unroll
        for (int ni = 0; ni < 4; ++ni)
          acc0[mi][ni] = MFMA16(af[mi], bfr[ni], acc0[mi][ni]);
    }
    {
      bf16x8 bfr[4];
#pragma unroll
      for (int ni = 0; ni < 4; ++ni)
        bfr[ni] = *(const bf16x8*)
            &Bs[cur][1][(wn * 64 + ni * 16 + lr) * 32 + kchunk];
#pragma unroll
      for (int mi = 0; mi < 4; ++mi)
#pragma unroll
        for (int ni = 0; ni < 4; ++ni)
          acc1[mi][ni] = MFMA16(af[mi], bfr[ni], acc1[mi][ni]);
    }
    {
      bf16x8 bfr[4];
#pragma unroll
      for (int ni = 0; ni < 4; ++ni)
        bfr[ni] = *(const bf16x8*)
            &Bs[cur][2][(wn * 64 + ni * 16 + lr) * 32 + kchunk];
#pragma unroll
      for (int mi = 0; mi < 4; ++mi)
#pragma unroll
        for (int ni = 0; ni < 4; ++ni)
          acc2[mi][ni] = MFMA16(af[mi], bfr[ni], acc2[mi][ni]);
    }

    if (pf) __builtin_amdgcn_s_barrier();
  }

  // ---- epilogue ----
  const int b = row0 >> 11;
  const int t0w = (row0 & (Tn - 1)) + wm * 64;   // wave's first t
  const int h = (col0 >> 6) + wn;                // wave's head

  // V^T (acc2): 4 consecutive t at fixed d -> one 8B store
#pragma unroll
  for (int mi = 0; mi < 4; ++mi) {
#pragma unroll
    for (int ni = 0; ni < 4; ++ni) {
      const int d = ni * 16 + lr;
      const float bv_ = bv[col0 + wn * 64 + d];
      const int t0 = t0w + mi * 16 + lg * 4;
      ushort4 o4;
      o4.x = f2bf(acc2[mi][ni][0] + bv_);
      o4.y = f2bf(acc2[mi][ni][1] + bv_);
      o4.z = f2bf(acc2[mi][ni][2] + bv_);
      o4.w = f2bf(acc2[mi][ni][3] + bv_);
      *(ushort4*)&Vo[(((size_t)b * Hn + h) * Dn + d) * Tn + t0] = o4;
    }
  }

  // Q/K via LDS transpose: wave-private [64][68] bf16 scratch in Bs
  __syncthreads();
  unsigned short* epi = &Bs[0][0][0] + w * 4352;

  // Q (pre-scaled)
  {
#pragma unroll
    for (int mi = 0; mi < 4; ++mi)
#pragma unroll
      for (int ni = 0; ni < 4; ++ni) {
        const float bv_ = bq[col0 + wn * 64 + ni * 16 + lr];
#pragma unroll
        for (int r = 0; r < 4; ++r)
          epi[(mi * 16 + lg * 4 + r) * 68 + ni * 16 + lr] =
              f2bf((acc0[mi][ni][r] + bv_) * kQScale);
      }
    asm volatile("s_waitcnt lgkmcnt(0)" ::: "memory");
#pragma unroll
    for (int j = 0; j < 8; ++j) {
      const int t = (lane >> 3) + 8 * j;
      const int ck = lane & 7;
      const bf16x8 v = *(const bf16x8*)&epi[t * 68 + ck * 8];
      *(bf16x8*)&Qo[((((size_t)b * Hn + h) * Tn + t0w + t) << 6) + ck * 8] = v;
    }
  }
  // K
  {
#pragma unroll
    for (int mi = 0; mi < 4; ++mi)
#pragma unroll
      for (int ni = 0; ni < 4; ++ni) {
        const float bv_ = bk[col0 + wn * 64 + ni * 16 + lr];
#pragma unroll
        for (int r = 0; r < 4; ++r)
          epi[(mi * 16 + lg * 4 + r) * 68 + ni * 16 + lr] =
              f2bf(acc1[mi][ni][r] + bv_);
      }
    asm volatile("s_waitcnt lgkmcnt(0)" ::: "memory");
#pragma unroll
    for (int j = 0; j < 8; ++j) {
      const int t = (lane >> 3) + 8 * j;
      const int ck = lane & 7;
      const bf16x8 v = *(const bf16x8*)&epi[t * 68 + ck * 8];
      *(bf16x8*)&Ko[((((size_t)b * Hn + h) * Tn + t0w + t) << 6) + ck * 8] = v;
    }
  }
}

// ---------------------------------------------------------------------------
// Output projection: fp32 out = Yb @ Wpt^T + bp.  Grid (64, 8).
// ---------------------------------------------------------------------------
__global__ __launch_bounds__(256, 2) void proj_gemm_k(
    const unsigned short* __restrict__ A, const unsigned short* __restrict__ Bt,
    const float* __restrict__ bias, float* __restrict__ out) {
  __shared__ unsigned short As[2 * 128 * 64];
  __shared__ unsigned short Bs[2 * 128 * 64];
  const int row0 = blockIdx.x * 128, col0 = blockIdx.y * 128;
  const f32x4 fz = {0.f, 0.f, 0.f, 0.f};
  f32x4 acc[4][4];
#pragma unroll
  for (int i = 0; i < 4; ++i)
#pragma unroll
    for (int j = 0; j < 4; ++j) acc[i][j] = fz;

  gemm_core(A, Bt, row0, col0, As, Bs, acc);

  const int lane = threadIdx.x & 63, w = threadIdx.x >> 6;
  const int wm = w >> 1, wn = w & 1;
  const int lr = lane & 15, lg = lane >> 4;
#pragma unroll
  for (int mi = 0; mi < 4; ++mi) {
#pragma unroll
    for (int ni = 0; ni < 4; ++ni) {
      const int col = col0 + wn * 64 + ni * 16 + lr;
      const float bv_ = bias[col];
#pragma unroll
      for (int r = 0; r < 4; ++r) {
        const int row = row0 + wm * 64 + mi * 16 + lg * 4 + r;
        out[(size_t)row * Cn + col] = acc[mi][ni][r] + bv_;
      }
    }
  }
}

// ---------------------------------------------------------------------------
// Flash attention (R19, unchanged): bf16 MFMA, swapped-QK^T, exp2-direct
// softmax, single-buffer V (32 KB LDS), l via MFMA (P . ones).
// Grid (64, 32): XCD = bh%8; qt reversed (LPT). Y epilogue via LDS-transpose.
// ---------------------------------------------------------------------------
__global__ __launch_bounds__(256, 4) void attn_mfma_k(
    const unsigned short* __restrict__ Q, const unsigned short* __restrict__ K,
    const unsigned short* __restrict__ Vt, unsigned short* __restrict__ Y) {
  __shared__ unsigned short Ks[2][64 * 64];   // 16 KB
  __shared__ unsigned short Vs[64 * 64];      //  8 KB (V^T tile: [d][key])
  __shared__ unsigned short Ps[4][16 * 64];   //  8 KB per-wave P: [q][key]
  const int tid = threadIdx.x, lane = tid & 63, w = tid >> 6;
  const int lr = lane & 15, lg = lane >> 4;
  const int bh = blockIdx.x;                       // XCD-local heads
  const int qt = (int)gridDim.y - 1 - blockIdx.y;  // heavy blocks first
  const size_t base = (size_t)bh * Tn * Dn;

  bf16x8 qf[2];
  const int qrow = qt * 64 + w * 16 + lr;   // this lane's q (global)
#pragma unroll
  for (int ks = 0; ks < 2; ++ks)
    qf[ks] = *(const bf16x8*)&Q[base + (size_t)qrow * Dn + ks * 32 + lg * 8];

  // constant all-ones bf16 fragment (B operand for the l-MFMA)
  const short one_bf = (short)0x3F80;
  const bf16x8 onesf = {one_bf, one_bf, one_bf, one_bf,
                        one_bf, one_bf, one_bf, one_bf};

  auto stage_K = [&](int buf, int kt) {
#pragma unroll
    for (int it = 0; it < 2; ++it) {
      const int c = it * 256 + tid;
      const int r = c >> 3;
      const int lc = (c & 7) ^ (r & 7);
      load_lds16(K + base + (size_t)(kt * 64 + r) * Dn + lc * 8, &Ks[buf][c * 8]);
    }
  };
  auto stage_V = [&](int kt) {
#pragma unroll
    for (int it = 0; it < 2; ++it) {
      const int c = it * 256 + tid;
      const int r = c >> 3;
      const int lc = (c & 7) ^ (r & 7);
      load_lds16(Vt + base + (size_t)r * Tn + kt * 64 + lc * 8, &Vs[c * 8]);
    }
  };

  const f32x4 fz = {0.f, 0.f, 0.f, 0.f};
  f32x4 oacc[4];
#pragma unroll
  for (int i = 0; i < 4; ++i) oacc[i] = fz;
  f32x4 acc_l = fz;   // l[q=lg*4+i] accumulated on the MFMA pipe

  // prologue: K(0) only (V(0) staged inside iteration 0)
  stage_K(0, 0);
  asm volatile("s_waitcnt vmcnt(0)" ::: "memory");
  __builtin_amdgcn_s_barrier();

  for (int kt = 0; kt <= qt; ++kt) {
    const int cur = kt & 1;
    const bool pf = (kt < qt);
    stage_V(kt);                       // V for THIS tile (drained mid-iter)
    if (pf) stage_K(cur ^ 1, kt + 1);  // K prefetch (drained end-of-iter)

    // ---- S^T = K . Q^T ----
    f32x4 s[4];
#pragma unroll
    for (int ni = 0; ni < 4; ++ni) s[ni] = fz;
    __builtin_amdgcn_s_setprio(1);
#pragma unroll
    for (int ni = 0; ni < 4; ++ni)
#pragma unroll
      for (int ks = 0; ks < 2; ++ks) {
        const bf16x8 kf = *(const bf16x8*)
            &Ks[cur][(ni * 16 + lr) * 64 + (((ks * 4 + lg) ^ (lr & 7)) << 3)];
        s[ni] = MFMA16(kf, qf[ks], s[ni]);
      }
    __builtin_amdgcn_s_setprio(0);

    const bool diag = (kt == qt);
    uint2 pw[4];
#pragma unroll
    for (int ni = 0; ni < 4; ++ni) {
      float p[4];
#pragma unroll
      for (int r = 0; r < 4; ++r) {
        float v = s[ni][r];
        if (diag) {
          const int gk = kt * 64 + ni * 16 + lg * 4 + r;
          if (gk > qrow) v = -1e30f;  // exp2 -> 0
        }
        p[r] = exp2f(v);
      }
      pw[ni].x = cvtpk_bf16(p[0], p[1]);
      pw[ni].y = cvtpk_bf16(p[2], p[3]);
    }

#pragma unroll
    for (int ni = 0; ni < 4; ++ni) {
      const int byte = lr * 128 + ((((ni * 2) + (lg >> 1)) ^ (lr & 7)) << 4) +
                       ((lg & 1) << 3);
      *(uint2*)((char*)&Ps[w][0] + byte) = pw[ni];
    }

    // ---- mid wait: V(kt) done (issued first this iter -> oldest) ----
    if (pf) asm volatile("s_waitcnt vmcnt(2)" ::: "memory");
    else    asm volatile("s_waitcnt vmcnt(0)" ::: "memory");
    __builtin_amdgcn_s_barrier();

    // ---- PV (+ l = P . ones on the MFMA pipe) ----
    __builtin_amdgcn_s_setprio(1);
#pragma unroll
    for (int ks = 0; ks < 2; ++ks) {
      const bf16x8 pa = *(const bf16x8*)
          &Ps[w][lr * 64 + (((ks * 4 + lg) ^ (lr & 7)) << 3)];
      acc_l = MFMA16(pa, onesf, acc_l);
#pragma unroll
      for (int nd = 0; nd < 4; ++nd) {
        const bf16x8 vf = *(const bf16x8*)
            &Vs[(nd * 16 + lr) * 64 + (((ks * 4 + lg) ^ (lr & 7)) << 3)];
        oacc[nd] = MFMA16(pa, vf, oacc[nd]);
      }
    }
    __builtin_amdgcn_s_setprio(0);

    // ---- end: K(kt+1) done (issued ~500cy ago); protect Vs/Ks WAR ----
    if (pf) {
      asm volatile("s_waitcnt vmcnt(0)" ::: "memory");
      __builtin_amdgcn_s_barrier();
    }
  }

  // epilogue: acc_l[i] = l for q = lg*4+i (no cross-lane reduce needed).
  const int b = bh >> 4, h = bh & 15;
  unsigned short* epi = &Ks[0][0] + w * 1152;
#pragma unroll
  for (int i = 0; i < 4; ++i) {
    const float inv = 1.f / acc_l[i];
#pragma unroll
    for (int nd = 0; nd < 4; ++nd)
      epi[(lg * 4 + i) * 68 + nd * 16 + lr] = f2bf(oacc[nd][i] * inv);
  }
  asm volatile("s_waitcnt lgkmcnt(0)" ::: "memory");
#pragma unroll
  for (int j = 0; j < 2; ++j) {
    const int tl = lane >> 2;
    const int ck = (lane & 3) + 4 * j;
    const bf16x8 v = *(const bf16x8*)&epi[tl * 68 + ck * 8];
    const int t = qt * 64 + w * 16 + tl;
    *(bf16x8*)&Y[((size_t)b * Tn + t) * Cn + h * Dn + ck * 8] = v;
  }
}

// ---------------------------------------------------------------------------
extern "C" void kernel_launch(void* const* d_in, const int* in_sizes, int n_in,
                              void* d_out, int out_size, void* d_ws, size_t ws_size,
                              hipStream_t stream) {
  const float* x  = (const float*)d_in[0];
  const float* Wq = (const float*)d_in[1];
  const float* bq = (const float*)d_in[2];
  const float* Wk = (const float*)d_in[3];
  const float* bk = (const float*)d_in[4];
  const float* Wv = (const float*)d_in[5];
  const float* bv = (const float*)d_in[6];
  const float* Wp = (const float*)d_in[7];
  const float* bp = (const float*)d_in[8];
  float* out = (float*)d_out;

  const size_t xe = (size_t)Bsz * Tn * Cn;  // 8,388,608
  const size_t we = (size_t)Cn * Cn;        // 1,048,576
  unsigned short* p = (unsigned short*)d_ws;
  unsigned short* xb  = p; p += xe;
  unsigned short* Wqt = p; p += we;
  unsigned short* Wkt = p; p += we;
  unsigned short* Wvt = p; p += we;
  unsigned short* Wpt = p; p += we;
  unsigned short* Qb  = p; p += xe;
  unsigned short* Kb  = p; p += xe;
  unsigned short* Vtb = p; p += xe;
  unsigned short* Yb  = p; p += xe;

  prep_k<<<dim3(16, 16, 20), dim3(256), 0, stream>>>(
      x, xb, Wq, Wk, Wv, Wp, Wqt, Wkt, Wvt, Wpt);

  qkv_fused_k<<<dim3((Bsz * Tn) / 128, Cn / 128), dim3(256), 0, stream>>>(
      xb, Wqt, Wkt, Wvt, bq, bk, bv, Qb, Kb, Vtb);

  attn_mfma_k<<<dim3(Bsz * Hn, Tn / 64), dim3(256), 0, stream>>>(Qb, Kb, Vtb, Yb);

  proj_gemm_k<<<dim3((Bsz * Tn) / 128, Cn / 128), dim3(256), 0, stream>>>(
      Yb, Wpt, bp, out);
}